// Round 7
// baseline (1296.694 us; speedup 1.0000x reference)
//
#include <hip/hip_runtime.h>

typedef unsigned int uint;
typedef unsigned short ushort;
typedef short short8 __attribute__((ext_vector_type(8)));
typedef float f32x4 __attribute__((ext_vector_type(4)));
typedef float float4u __attribute__((ext_vector_type(4), aligned(4)));

#define MN 100000
#define ME 1600000
#define KIN 770

__device__ __forceinline__ ushort f2bf(float f) {
    union { float f; uint u; } c; c.f = f;
    uint r = (c.u + 0x7fffu + ((c.u >> 16) & 1u)) >> 16;
    return (ushort)r;
}
__device__ __forceinline__ float bf2f(ushort h) {
    union { uint u; float f; } c; c.u = ((uint)h) << 16;
    return c.f;
}
__device__ __forceinline__ float bflo(uint w) {
    union { uint u; float f; } c; c.u = w << 16; return c.f;
}
__device__ __forceinline__ float bfhi(uint w) {
    union { uint u; float f; } c; c.u = w & 0xffff0000u; return c.f;
}

// ---------------------------------------------------------------- CSR build
__global__ void k_deg(const int* __restrict__ dstv, int* __restrict__ deg, int E) {
    int e = blockIdx.x * blockDim.x + threadIdx.x;
    if (e < E) atomicAdd(&deg[dstv[e]], 1);
}

__global__ void k_scan1(const int* __restrict__ deg, int* __restrict__ excl,
                        int* __restrict__ csums, int n) {
    __shared__ int a[256], b[256];
    int tid = threadIdx.x;
    int g = blockIdx.x * 256 + tid;
    int v = (g < n) ? deg[g] : 0;
    int *cur = a, *nxt = b;
    cur[tid] = v;
    __syncthreads();
    for (int off = 1; off < 256; off <<= 1) {
        int t = cur[tid];
        if (tid >= off) t += cur[tid - off];
        nxt[tid] = t;
        __syncthreads();
        int* tmp = cur; cur = nxt; nxt = tmp;
    }
    int inc = cur[tid];
    if (g < n) excl[g] = inc - v;
    if (tid == 255) csums[blockIdx.x] = inc;
}

__global__ void k_scan2(int* __restrict__ csums, int nchunks) {
    __shared__ int a[512], b[512];
    int tid = threadIdx.x;
    int v = (tid < nchunks) ? csums[tid] : 0;
    int *cur = a, *nxt = b;
    cur[tid] = v;
    __syncthreads();
    for (int off = 1; off < 512; off <<= 1) {
        int t = cur[tid];
        if (tid >= off) t += cur[tid - off];
        nxt[tid] = t;
        __syncthreads();
        int* tmp = cur; cur = nxt; nxt = tmp;
    }
    int inc = cur[tid];
    if (tid < nchunks) csums[tid] = inc - v;
}

__global__ void k_scan3(int* __restrict__ row_ptr, const int* __restrict__ csums,
                        int* __restrict__ cursor, int n, int E) {
    int g = blockIdx.x * blockDim.x + threadIdx.x;
    if (g < n) {
        int v = row_ptr[g] + csums[g >> 8];
        row_ptr[g] = v;
        cursor[g] = v;
    }
    if (g == n) row_ptr[n] = E;
}

// scatter edges into CSR slots; esrt = src | rel<<17; dstp = dst; eid = original edge id
__global__ void k_fill(const int* __restrict__ srcv, const int* __restrict__ dstv,
                       const int* __restrict__ et, int* __restrict__ cursor,
                       int* __restrict__ esrt, int* __restrict__ dstp,
                       int* __restrict__ eid, int E) {
    int e = blockIdx.x * blockDim.x + threadIdx.x;
    if (e < E) {
        int d = dstv[e];
        int pos = atomicAdd(&cursor[d], 1);
        esrt[pos] = srcv[e] | (et[e] << 17);
        dstp[pos] = d;
        eid[pos] = e;
    }
}

// ---------------------------------------------------------------- weight packing (B^T bf16)
__global__ void k_pack_bt(const float* __restrict__ root, const float* __restrict__ W,
                          ushort* __restrict__ out, int K, int Kp) {
    int idx = blockIdx.x * blockDim.x + threadIdx.x;
    if (idx >= 256 * Kp) return;
    int j = idx / Kp, k = idx - j * Kp;
    float v = 0.f;
    if (k < K) {
        if (j < 64) v = root[k * 64 + j];
        else {
            int r = (j >> 6) - 1, jj = j & 63;
            v = W[((size_t)r * K + k) * 64 + jj];
        }
    }
    out[idx] = f2bf(v);
}

__global__ void k_packwab_bt(const float* __restrict__ ew1, ushort* __restrict__ out) {
    int idx = blockIdx.x * blockDim.x + threadIdx.x;
    if (idx >= 128 * 64) return;
    int j = idx >> 6, k = idx & 63;
    float v = (j < 64) ? ew1[k * 64 + j] : ew1[(64 + k) * 64 + (j - 64)];
    out[idx] = f2bf(v);
}

// ---------------------------------------------------------------- bf16 MFMA GEMM (BK=64)
// C[M,Nc](bf16) = A[M,K] @ BT[Nc,Kp]^T.  BM=128, BK=64, 512 thr (8 waves 2x4).
// Staging: lane covers 16B(bf16)/32B(fp32) of one row; 8 lanes = full 64-k span of a row.
//   A wave-load: 8 rows x 256B contiguous segments. B wave-load: 8 cols x 128B.
// LDS (uint4 slots): As[h][kq][128] at 0..1023; Bs[h][kq][BN] at 1024.. (h=k32 half).
// Frag reads keep R5-proven k-slot-major pattern: slot mod 8 == l15 mod 8 (uniform banks).
template<bool AFP32, int BN>
__global__ __launch_bounds__(512) void k_mm(const void* __restrict__ Ain,
                                            const ushort* __restrict__ BT,
                                            ushort* __restrict__ C,
                                            int M, int K, int Kp, int Nc) {
    constexpr int WN = BN / 4;
    constexpr int NF = WN / 16;
    constexpr int BR = BN / 64;            // B staging rounds
    __shared__ uint4 lds4[1024 + 8 * BN];  // As: 2*4*128, Bs: 2*4*BN
    int tid = threadIdx.x;
    int lane = tid & 63, wid = tid >> 6;
    int l15 = lane & 15, kqw = lane >> 4;  // compute-side frag coords
    int wm = wid >> 2, wn = wid & 3;
    int m0 = blockIdx.x * 128;
    int n0 = blockIdx.y * BN;

    // staging coords: 8 lanes per row/col, g = k-group (16B bf16 each)
    int s_g = tid & 7;                     // 0..7 -> k offset g*8 elems
    int s_h = s_g >> 2, s_kq = s_g & 3;    // LDS half / kq slot
    int s_r = tid >> 3;                    // 0..63 (round adds 64)

    const float*  Af = (const float*)Ain;
    const ushort* Ab = (const ushort*)Ain;

    f32x4 acc[4][NF];
    #pragma unroll
    for (int m = 0; m < 4; ++m)
        #pragma unroll
        for (int n = 0; n < NF; ++n)
            acc[m][n] = (f32x4)0.f;

    int nkt = (K + 63) >> 6;
    float stAf[2][8];
    uint4 stAb[2];
    uint4 stB[BR];

    auto loadA = [&](int kt) {
        int k0 = kt << 6;
        int kb = k0 + s_g * 8;
        #pragma unroll
        for (int r = 0; r < 2; ++r) {
            int gm = m0 + s_r + (r << 6);
            if (gm > M - 1) gm = M - 1;
            if constexpr (AFP32) {
                const float* ap = Af + (size_t)gm * K + kb;
                if (k0 + 64 <= K) {
                    *(float4u*)&stAf[r][0] = *(const float4u*)ap;
                    *(float4u*)&stAf[r][4] = *(const float4u*)(ap + 4);
                } else {
                    #pragma unroll
                    for (int i = 0; i < 8; ++i)
                        stAf[r][i] = (kb + i < K) ? ap[i] : 0.f;
                }
            } else {
                stAb[r] = *(const uint4*)(Ab + (size_t)gm * K + kb);
            }
        }
    };
    auto loadB = [&](int kt) {
        int k0 = kt << 6;
        #pragma unroll
        for (int r = 0; r < BR; ++r) {
            int col = s_r + (r << 6);
            stB[r] = *(const uint4*)(BT + (size_t)(n0 + col) * Kp + k0 + s_g * 8);
        }
    };

    loadA(0); loadB(0);
    for (int kt = 0; kt < nkt; ++kt) {
        __syncthreads();
        // A -> LDS
        #pragma unroll
        for (int r = 0; r < 2; ++r) {
            uint4 val;
            if constexpr (AFP32) {
                uint w0 = (uint)f2bf(stAf[r][0]) | ((uint)f2bf(stAf[r][1]) << 16);
                uint w1 = (uint)f2bf(stAf[r][2]) | ((uint)f2bf(stAf[r][3]) << 16);
                uint w2 = (uint)f2bf(stAf[r][4]) | ((uint)f2bf(stAf[r][5]) << 16);
                uint w3 = (uint)f2bf(stAf[r][6]) | ((uint)f2bf(stAf[r][7]) << 16);
                val = make_uint4(w0, w1, w2, w3);
            } else {
                val = stAb[r];
            }
            lds4[s_h * 512 + s_kq * 128 + s_r + (r << 6)] = val;
        }
        // B -> LDS
        #pragma unroll
        for (int r = 0; r < BR; ++r)
            lds4[1024 + s_h * (4 * BN) + s_kq * BN + s_r + (r << 6)] = stB[r];
        __syncthreads();
        if (kt + 1 < nkt) { loadA(kt + 1); loadB(kt + 1); }
        const short8* Asv = (const short8*)lds4;
        #pragma unroll
        for (int h = 0; h < 2; ++h) {
            short8 a[4], b[NF];
            #pragma unroll
            for (int m = 0; m < 4; ++m)
                a[m] = Asv[h * 512 + kqw * 128 + wm * 64 + m * 16 + l15];
            #pragma unroll
            for (int n = 0; n < NF; ++n)
                b[n] = Asv[1024 + h * (4 * BN) + kqw * BN + wn * WN + n * 16 + l15];
            #pragma unroll
            for (int m = 0; m < 4; ++m)
                #pragma unroll
                for (int n = 0; n < NF; ++n)
                    acc[m][n] = __builtin_amdgcn_mfma_f32_16x16x32_bf16(a[m], b[n], acc[m][n], 0, 0, 0);
        }
    }

    #pragma unroll
    for (int m = 0; m < 4; ++m) {
        int rbase = m0 + wm * 64 + m * 16 + kqw * 4;
        #pragma unroll
        for (int n = 0; n < NF; ++n) {
            int col = n0 + wn * WN + n * 16 + l15;
            #pragma unroll
            for (int rg = 0; rg < 4; ++rg) {
                int r = rbase + rg;
                if (r < M) C[(size_t)r * Nc + col] = f2bf(acc[m][n][rg]);
            }
        }
    }
}

// ---------------------------------------------------------------- RGCN aggregation (bf16)
__global__ __launch_bounds__(256) void k_agg(const ushort* __restrict__ Y,
                                             const int* __restrict__ row_ptr,
                                             const int* __restrict__ esrt,
                                             const float* __restrict__ bias,
                                             const ushort* __restrict__ resid,
                                             ushort* __restrict__ Xout,
                                             int do_relu, int n) {
    int wid = (blockIdx.x * blockDim.x + threadIdx.x) >> 6;
    int lane = threadIdx.x & 63;
    if (wid >= n) return;
    int beg = row_ptr[wid], end = row_ptr[wid + 1];
    float self = bf2f(Y[(size_t)wid * 256 + lane]);
    float bv = bias[lane];
    float a0 = 0.f, a1 = 0.f, a2 = 0.f;
    int c0 = 0, c1 = 0, c2 = 0;
    int e = beg;
    for (; e + 4 <= end; e += 4) {
        int p0 = esrt[e], p1 = esrt[e + 1], p2 = esrt[e + 2], p3 = esrt[e + 3];
        float v0 = bf2f(Y[(size_t)(p0 & 0x1FFFF) * 256 + 64 + ((p0 >> 17) << 6) + lane]);
        float v1 = bf2f(Y[(size_t)(p1 & 0x1FFFF) * 256 + 64 + ((p1 >> 17) << 6) + lane]);
        float v2 = bf2f(Y[(size_t)(p2 & 0x1FFFF) * 256 + 64 + ((p2 >> 17) << 6) + lane]);
        float v3 = bf2f(Y[(size_t)(p3 & 0x1FFFF) * 256 + 64 + ((p3 >> 17) << 6) + lane]);
        int r0 = p0 >> 17, r1 = p1 >> 17, r2 = p2 >> 17, r3 = p3 >> 17;
        if (r0 == 0) { a0 += v0; c0++; } else if (r0 == 1) { a1 += v0; c1++; } else { a2 += v0; c2++; }
        if (r1 == 0) { a0 += v1; c0++; } else if (r1 == 1) { a1 += v1; c1++; } else { a2 += v1; c2++; }
        if (r2 == 0) { a0 += v2; c0++; } else if (r2 == 1) { a1 += v2; c1++; } else { a2 += v2; c2++; }
        if (r3 == 0) { a0 += v3; c0++; } else if (r3 == 1) { a1 += v3; c1++; } else { a2 += v3; c2++; }
    }
    for (; e < end; ++e) {
        int p = esrt[e];
        int r = p >> 17;
        float v = bf2f(Y[(size_t)(p & 0x1FFFF) * 256 + 64 + (r << 6) + lane]);
        if (r == 0) { a0 += v; c0++; } else if (r == 1) { a1 += v; c1++; } else { a2 += v; c2++; }
    }
    float res = self + bv;
    if (c0) res += a0 / (float)c0;
    if (c1) res += a1 / (float)c1;
    if (c2) res += a2 / (float)c2;
    if (do_relu) res = fmaxf(res, 0.f);
    if (resid) res += bf2f(resid[(size_t)wid * 64 + lane]);
    Xout[(size_t)wid * 64 + lane] = f2bf(res);
}

// ---------------------------------------------------------------- node head
__global__ __launch_bounds__(256) void k_nodehead(const ushort* __restrict__ X3,
                                                  const float* __restrict__ nw1,
                                                  const float* __restrict__ nb1,
                                                  const float* __restrict__ nw2,
                                                  const float* __restrict__ nb2,
                                                  float* __restrict__ out, int n) {
    __shared__ float w1[64 * 32];
    __shared__ float w2[32 * 2];
    __shared__ float b1s[32];
    __shared__ float b2s[2];
    int tid = threadIdx.x;
    for (int i = tid; i < 64 * 32; i += 256) w1[i] = nw1[i];
    for (int i = tid; i < 32 * 2; i += 256) w2[i] = nw2[i];
    if (tid < 32) b1s[tid] = nb1[tid];
    if (tid < 2) b2s[tid] = nb2[tid];
    __syncthreads();
    int g = blockIdx.x * blockDim.x + tid;
    if (g >= n) return;
    float x[64];
    const uint4* xr = (const uint4*)(X3 + (size_t)g * 64);
    #pragma unroll
    for (int q = 0; q < 8; ++q) {
        uint4 u = xr[q];
        x[q * 8 + 0] = bflo(u.x); x[q * 8 + 1] = bfhi(u.x);
        x[q * 8 + 2] = bflo(u.y); x[q * 8 + 3] = bfhi(u.y);
        x[q * 8 + 4] = bflo(u.z); x[q * 8 + 5] = bfhi(u.z);
        x[q * 8 + 6] = bflo(u.w); x[q * 8 + 7] = bfhi(u.w);
    }
    float o0 = b2s[0], o1 = b2s[1];
    for (int j = 0; j < 32; ++j) {
        float h = b1s[j];
        #pragma unroll
        for (int k = 0; k < 64; ++k) h += x[k] * w1[k * 32 + j];
        h = fmaxf(h, 0.f);
        o0 += h * w2[j * 2 + 0];
        o1 += h * w2[j * 2 + 1];
    }
    out[g * 2 + 0] = o0;
    out[g * 2 + 1] = o1;
}

// ---------------------------------------------------------------- edge head (dst-sorted)
__global__ __launch_bounds__(256) void k_edgehead(const ushort* __restrict__ AB,
                                                  const int* __restrict__ esrt,
                                                  const int* __restrict__ dstp,
                                                  const int* __restrict__ eid,
                                                  const float* __restrict__ eb1,
                                                  const float* __restrict__ ew2,
                                                  const float* __restrict__ eb2,
                                                  const float* __restrict__ ew3,
                                                  const float* __restrict__ eb3,
                                                  float* __restrict__ out, int E) {
    __shared__ float w2[64 * 32];
    __shared__ float w3[32 * 3];
    __shared__ float b1s[64];
    __shared__ float b2s[32];
    __shared__ float b3s[3];
    int tid = threadIdx.x;
    for (int i = tid; i < 64 * 32; i += 256) w2[i] = ew2[i];
    for (int i = tid; i < 32 * 3; i += 256) w3[i] = ew3[i];
    if (tid < 64) b1s[tid] = eb1[tid];
    if (tid < 32) b2s[tid] = eb2[tid];
    if (tid < 3) b3s[tid] = eb3[tid];
    __syncthreads();
    int p = blockIdx.x * blockDim.x + tid;
    if (p >= E) return;
    int s = esrt[p] & 0x1FFFF;
    int d = dstp[p];
    int e = eid[p];
    const uint4* Ar = (const uint4*)(AB + (size_t)s * 128);
    uint4 a4[8];
    #pragma unroll
    for (int q = 0; q < 8; ++q) a4[q] = Ar[q];
    const uint4* Br = (const uint4*)(AB + (size_t)d * 128 + 64);
    float h2[32];
    #pragma unroll
    for (int j = 0; j < 32; ++j) h2[j] = 0.f;
    #pragma unroll
    for (int q = 0; q < 8; ++q) {
        uint4 ua = a4[q], ub = Br[q];
        float af[8], bfv[8];
        af[0] = bflo(ua.x); af[1] = bfhi(ua.x); af[2] = bflo(ua.y); af[3] = bfhi(ua.y);
        af[4] = bflo(ua.z); af[5] = bfhi(ua.z); af[6] = bflo(ua.w); af[7] = bfhi(ua.w);
        bfv[0] = bflo(ub.x); bfv[1] = bfhi(ub.x); bfv[2] = bflo(ub.y); bfv[3] = bfhi(ub.y);
        bfv[4] = bflo(ub.z); bfv[5] = bfhi(ub.z); bfv[6] = bflo(ub.w); bfv[7] = bfhi(ub.w);
        #pragma unroll
        for (int t = 0; t < 8; ++t) {
            int k = q * 8 + t;
            float h1 = fmaxf(af[t] + bfv[t] + b1s[k], 0.f);
            #pragma unroll
            for (int j = 0; j < 32; ++j) h2[j] += h1 * w2[k * 32 + j];
        }
    }
    float o0 = b3s[0], o1 = b3s[1], o2 = b3s[2];
    #pragma unroll
    for (int j = 0; j < 32; ++j) {
        float hh = fmaxf(h2[j] + b2s[j], 0.f);
        o0 += hh * w3[j * 3 + 0];
        o1 += hh * w3[j * 3 + 1];
        o2 += hh * w3[j * 3 + 2];
    }
    out[200000 + (size_t)e * 3 + 0] = o0;
    out[200000 + (size_t)e * 3 + 1] = o1;
    out[200000 + (size_t)e * 3 + 2] = o2;
}

// ---------------------------------------------------------------- launch
extern "C" void kernel_launch(void* const* d_in, const int* in_sizes, int n_in,
                              void* d_out, int out_size, void* d_ws, size_t ws_size,
                              hipStream_t stream) {
    const float* x     = (const float*)d_in[0];
    const int*   ei    = (const int*)d_in[1];
    const int*   et    = (const int*)d_in[2];
    const float* W1    = (const float*)d_in[3];
    const float* root1 = (const float*)d_in[4];
    const float* b1    = (const float*)d_in[5];
    const float* W2    = (const float*)d_in[6];
    const float* root2 = (const float*)d_in[7];
    const float* b2    = (const float*)d_in[8];
    const float* W3    = (const float*)d_in[9];
    const float* root3 = (const float*)d_in[10];
    const float* b3    = (const float*)d_in[11];
    const float* nw1   = (const float*)d_in[12];
    const float* nb1   = (const float*)d_in[13];
    const float* nw2   = (const float*)d_in[14];
    const float* nb2   = (const float*)d_in[15];
    const float* ew1   = (const float*)d_in[16];
    const float* eb1   = (const float*)d_in[17];
    const float* ew2   = (const float*)d_in[18];
    const float* eb2   = (const float*)d_in[19];
    const float* ew3   = (const float*)d_in[20];
    const float* eb3   = (const float*)d_in[21];
    float* out = (float*)d_out;

    const int N = MN, E = ME;
    const int* srcv = ei;
    const int* dstv = ei + E;

    char* w = (char*)d_ws;
    ushort* Yb   = (ushort*)w; w += (size_t)N * 256 * 2;
    ushort* X1b  = (ushort*)w; w += (size_t)N * 64 * 2;
    ushort* X2b  = (ushort*)w; w += (size_t)N * 64 * 2;
    ushort* X3b  = (ushort*)w; w += (size_t)N * 64 * 2;
    ushort* ABb  = (ushort*)w; w += (size_t)N * 128 * 2;
    ushort* BT1  = (ushort*)w; w += 256 * 832 * 2;
    ushort* BT2  = (ushort*)w; w += 256 * 64 * 2;
    ushort* BT3  = (ushort*)w; w += 256 * 64 * 2;
    ushort* BTab = (ushort*)w; w += 128 * 64 * 2;
    int* deg     = (int*)w; w += (size_t)N * 4;
    int* row_ptr = (int*)w; w += (size_t)(N + 1) * 4;
    int* cursor  = (int*)w; w += (size_t)N * 4;
    int* esrt    = (int*)w; w += (size_t)E * 4;
    int* dstp    = (int*)w; w += (size_t)E * 4;
    int* eid     = (int*)w; w += (size_t)E * 4;
    int* csums   = (int*)w; w += 512 * 4;

    // ---- CSR build
    hipMemsetAsync(deg, 0, N * sizeof(int), stream);
    k_deg<<<(E + 255) / 256, 256, 0, stream>>>(dstv, deg, E);
    int nchunks = (N + 255) / 256;
    k_scan1<<<nchunks, 256, 0, stream>>>(deg, row_ptr, csums, N);
    k_scan2<<<1, 512, 0, stream>>>(csums, nchunks);
    k_scan3<<<(N + 256) / 256, 256, 0, stream>>>(row_ptr, csums, cursor, N, E);
    k_fill<<<(E + 255) / 256, 256, 0, stream>>>(srcv, dstv, et, cursor, esrt, dstp, eid, E);

    // ---- weight packs (bf16 B^T); BT1 Kp=832 (13 x 64-k tiles, zero-padded)
    k_pack_bt<<<(256 * 832 + 255) / 256, 256, 0, stream>>>(root1, W1, BT1, KIN, 832);
    k_pack_bt<<<(256 * 64 + 255) / 256, 256, 0, stream>>>(root2, W2, BT2, 64, 64);
    k_pack_bt<<<(256 * 64 + 255) / 256, 256, 0, stream>>>(root3, W3, BT3, 64, 64);
    k_packwab_bt<<<(128 * 64 + 255) / 256, 256, 0, stream>>>(ew1, BTab);

    int gx = (N + 127) / 128;  // 782
    int agg_grid = (N * 64 + 255) / 256;

    // ---- layer 1 (A fp32 fused-convert)
    k_mm<true, 256><<<dim3(gx, 1), 512, 0, stream>>>(x, BT1, Yb, N, KIN, 832, 256);
    k_agg<<<agg_grid, 256, 0, stream>>>(Yb, row_ptr, esrt, b1, nullptr, X1b, 1, N);

    // ---- layer 2
    k_mm<false, 256><<<dim3(gx, 1), 512, 0, stream>>>(X1b, BT2, Yb, N, 64, 64, 256);
    k_agg<<<agg_grid, 256, 0, stream>>>(Yb, row_ptr, esrt, b2, nullptr, X2b, 1, N);

    // ---- layer 3 (+ residual X1, no relu)
    k_mm<false, 256><<<dim3(gx, 1), 512, 0, stream>>>(X2b, BT3, Yb, N, 64, 64, 256);
    k_agg<<<agg_grid, 256, 0, stream>>>(Yb, row_ptr, esrt, b3, X1b, X3b, 0, N);

    // ---- node head
    k_nodehead<<<(N + 255) / 256, 256, 0, stream>>>(X3b, nw1, nb1, nw2, nb2, out, N);

    // ---- edge head (dst-sorted order)
    k_mm<false, 128><<<dim3(gx, 1), 512, 0, stream>>>(X3b, BTab, ABb, N, 64, 64, 128);
    k_edgehead<<<(E + 255) / 256, 256, 0, stream>>>(ABb, esrt, dstp, eid, eb1, ew2, eb2, ew3, eb3, out, E);
}

// Round 8
// 1257.507 us; speedup vs baseline: 1.0312x; 1.0312x over previous
//
#include <hip/hip_runtime.h>

typedef unsigned int uint;
typedef unsigned short ushort;
typedef short short8 __attribute__((ext_vector_type(8)));
typedef float f32x4 __attribute__((ext_vector_type(4)));
typedef float float4u __attribute__((ext_vector_type(4), aligned(4)));

#define MN 100000
#define ME 1600000
#define KIN 770

__device__ __forceinline__ ushort f2bf(float f) {
    union { float f; uint u; } c; c.f = f;
    uint r = (c.u + 0x7fffu + ((c.u >> 16) & 1u)) >> 16;
    return (ushort)r;
}
__device__ __forceinline__ float bf2f(ushort h) {
    union { uint u; float f; } c; c.u = ((uint)h) << 16;
    return c.f;
}
__device__ __forceinline__ float bflo(uint w) {
    union { uint u; float f; } c; c.u = w << 16; return c.f;
}
__device__ __forceinline__ float bfhi(uint w) {
    union { uint u; float f; } c; c.u = w & 0xffff0000u; return c.f;
}

// ---------------------------------------------------------------- CSR build
__global__ void k_deg(const int* __restrict__ dstv, int* __restrict__ deg, int E) {
    int e = blockIdx.x * blockDim.x + threadIdx.x;
    if (e < E) atomicAdd(&deg[dstv[e]], 1);
}

__global__ void k_scan1(const int* __restrict__ deg, int* __restrict__ excl,
                        int* __restrict__ csums, int n) {
    __shared__ int a[256], b[256];
    int tid = threadIdx.x;
    int g = blockIdx.x * 256 + tid;
    int v = (g < n) ? deg[g] : 0;
    int *cur = a, *nxt = b;
    cur[tid] = v;
    __syncthreads();
    for (int off = 1; off < 256; off <<= 1) {
        int t = cur[tid];
        if (tid >= off) t += cur[tid - off];
        nxt[tid] = t;
        __syncthreads();
        int* tmp = cur; cur = nxt; nxt = tmp;
    }
    int inc = cur[tid];
    if (g < n) excl[g] = inc - v;
    if (tid == 255) csums[blockIdx.x] = inc;
}

__global__ void k_scan2(int* __restrict__ csums, int nchunks) {
    __shared__ int a[512], b[512];
    int tid = threadIdx.x;
    int v = (tid < nchunks) ? csums[tid] : 0;
    int *cur = a, *nxt = b;
    cur[tid] = v;
    __syncthreads();
    for (int off = 1; off < 512; off <<= 1) {
        int t = cur[tid];
        if (tid >= off) t += cur[tid - off];
        nxt[tid] = t;
        __syncthreads();
        int* tmp = cur; cur = nxt; nxt = tmp;
    }
    int inc = cur[tid];
    if (tid < nchunks) csums[tid] = inc - v;
}

__global__ void k_scan3(int* __restrict__ row_ptr, const int* __restrict__ csums,
                        int* __restrict__ cursor, int n, int E) {
    int g = blockIdx.x * blockDim.x + threadIdx.x;
    if (g < n) {
        int v = row_ptr[g] + csums[g >> 8];
        row_ptr[g] = v;
        cursor[g] = v;
    }
    if (g == n) row_ptr[n] = E;
}

__global__ void k_fill(const int* __restrict__ srcv, const int* __restrict__ dstv,
                       const int* __restrict__ et, int* __restrict__ cursor,
                       int* __restrict__ esrt, int* __restrict__ dstp,
                       int* __restrict__ eid, int E) {
    int e = blockIdx.x * blockDim.x + threadIdx.x;
    if (e < E) {
        int d = dstv[e];
        int pos = atomicAdd(&cursor[d], 1);
        esrt[pos] = srcv[e] | (et[e] << 17);
        dstp[pos] = d;
        eid[pos] = e;
    }
}

// ---------------------------------------------------------------- weight packing (bf16 B^T)
// Layer-1 wide pack: out[j][k] stride Kp; j<64 -> root, else W[(j>>6)-1][k][j&63]
__global__ void k_pack_bt(const float* __restrict__ root, const float* __restrict__ W,
                          ushort* __restrict__ out, int K, int Kp) {
    int idx = blockIdx.x * blockDim.x + threadIdx.x;
    if (idx >= 256 * Kp) return;
    int j = idx / Kp, k = idx - j * Kp;
    float v = 0.f;
    if (k < K) {
        if (j < 64) v = root[k * 64 + j];
        else {
            int r = (j >> 6) - 1, jj = j & 63;
            v = W[((size_t)r * K + k) * 64 + jj];
        }
    }
    out[idx] = f2bf(v);
}

// Stacked pack for agg-first layers: out[j][k] (64 x 256): k<64 -> root[k][j];
// else r=(k>>6)-1 -> W[r][k&63][j]
__global__ void k_pack_stack(const float* __restrict__ root, const float* __restrict__ W,
                             ushort* __restrict__ out) {
    int idx = blockIdx.x * blockDim.x + threadIdx.x;
    if (idx >= 64 * 256) return;
    int j = idx >> 8, k = idx & 255;
    float v;
    if (k < 64) v = root[k * 64 + j];
    else {
        int r = (k >> 6) - 1, kk = k & 63;
        v = W[((size_t)r * 64 + kk) * 64 + j];
    }
    out[idx] = f2bf(v);
}

// Edge-head packs: BTa[j][k]=ew1[k][j], BTb[j][k]=ew1[64+k][j]  (both 64x64)
__global__ void k_packab(const float* __restrict__ ew1, ushort* __restrict__ BTa,
                         ushort* __restrict__ BTb) {
    int idx = blockIdx.x * blockDim.x + threadIdx.x;
    if (idx >= 64 * 64) return;
    int j = idx >> 6, k = idx & 63;
    BTa[idx] = f2bf(ew1[k * 64 + j]);
    BTb[idx] = f2bf(ew1[(64 + k) * 64 + j]);
}

// ---------------------------------------------------------------- bf16 MFMA GEMM (R5-proven)
// C[M,Nc](bf16) = A[M,K] @ BT[Nc,Kp]^T.  BM=128, BK=32, 512 thr (8 waves 2x4).
// Optional fused epilogue: +bias[col], relu, +resid[r*Nc+col].
template<bool AFP32, int BN>
__global__ __launch_bounds__(512) void k_mm(const void* __restrict__ Ain,
                                            const ushort* __restrict__ BT,
                                            ushort* __restrict__ C,
                                            int M, int K, int Kp, int Nc,
                                            const float* __restrict__ bias,
                                            const ushort* __restrict__ resid,
                                            int do_relu) {
    constexpr int WN = BN / 4;
    constexpr int NF = WN / 16;
    constexpr int NBS = (4 * BN >= 512) ? (4 * BN) / 512 : 1;
    __shared__ uint4 lds4[512 + 4 * BN];
    int tid = threadIdx.x;
    int lane = tid & 63, wid = tid >> 6;
    int l15 = lane & 15, kq = lane >> 4;
    int wm = wid >> 2, wn = wid & 3;
    int m0 = blockIdx.x * 128;
    int n0 = blockIdx.y * BN;

    int s_kp = tid >> 7;       // 0..3
    int s_row = tid & 127;
    int gm = m0 + s_row; if (gm > M - 1) gm = M - 1;

    const float*  Af = (const float*)Ain;
    const ushort* Ab = (const ushort*)Ain;

    f32x4 acc[4][NF];
    #pragma unroll
    for (int m = 0; m < 4; ++m)
        #pragma unroll
        for (int n = 0; n < NF; ++n)
            acc[m][n] = (f32x4)0.f;

    int nkt = (K + 31) >> 5;
    uint4 stA, stB[NBS];

    auto loadA = [&](int kt) {
        int k0 = kt << 5;
        int kb = k0 + s_kp * 8;
        if constexpr (AFP32) {
            const float* ap = Af + (size_t)gm * K + kb;
            float v[8];
            if (k0 + 32 <= K) {
                *(float4u*)&v[0] = *(const float4u*)ap;
                *(float4u*)&v[4] = *(const float4u*)(ap + 4);
            } else {
                #pragma unroll
                for (int i = 0; i < 8; ++i)
                    v[i] = (kb + i < K) ? ap[i] : 0.f;
            }
            uint w[4];
            #pragma unroll
            for (int i = 0; i < 4; ++i)
                w[i] = (uint)f2bf(v[2 * i]) | ((uint)f2bf(v[2 * i + 1]) << 16);
            stA = make_uint4(w[0], w[1], w[2], w[3]);
        } else {
            stA = *(const uint4*)(Ab + (size_t)gm * K + kb);
        }
    };
    auto loadB = [&](int kt) {
        int k0 = kt << 5;
        if constexpr (BN >= 128) {
            #pragma unroll
            for (int is = 0; is < NBS; ++is) {
                int slot = is * 512 + tid;
                int kp = slot / BN;
                int col = slot & (BN - 1);
                stB[is] = *(const uint4*)(BT + (size_t)(n0 + col) * Kp + k0 + kp * 8);
            }
        } else {
            if (tid < 4 * BN) {
                int kp = tid / BN;
                int col = tid & (BN - 1);
                stB[0] = *(const uint4*)(BT + (size_t)(n0 + col) * Kp + k0 + kp * 8);
            }
        }
    };

    loadA(0); loadB(0);
    for (int kt = 0; kt < nkt; ++kt) {
        __syncthreads();
        lds4[tid] = stA;
        if constexpr (BN >= 128) {
            #pragma unroll
            for (int is = 0; is < NBS; ++is)
                lds4[512 + is * 512 + tid] = stB[is];
        } else {
            if (tid < 4 * BN) lds4[512 + tid] = stB[0];
        }
        __syncthreads();
        if (kt + 1 < nkt) { loadA(kt + 1); loadB(kt + 1); }
        const short8* Asv = (const short8*)lds4;
        const short8* Bsv = (const short8*)(lds4 + 512);
        short8 a[4], b[NF];
        #pragma unroll
        for (int m = 0; m < 4; ++m)
            a[m] = Asv[kq * 128 + wm * 64 + m * 16 + l15];
        #pragma unroll
        for (int n = 0; n < NF; ++n)
            b[n] = Bsv[kq * BN + wn * WN + n * 16 + l15];
        #pragma unroll
        for (int m = 0; m < 4; ++m)
            #pragma unroll
            for (int n = 0; n < NF; ++n)
                acc[m][n] = __builtin_amdgcn_mfma_f32_16x16x32_bf16(a[m], b[n], acc[m][n], 0, 0, 0);
    }

    #pragma unroll
    for (int m = 0; m < 4; ++m) {
        int rbase = m0 + wm * 64 + m * 16 + kq * 4;
        #pragma unroll
        for (int n = 0; n < NF; ++n) {
            int col = n0 + wn * WN + n * 16 + l15;
            float bv = bias ? bias[col] : 0.f;
            #pragma unroll
            for (int rg = 0; rg < 4; ++rg) {
                int r = rbase + rg;
                if (r < M) {
                    float v = acc[m][n][rg] + bv;
                    if (do_relu) v = fmaxf(v, 0.f);
                    if (resid) v += bf2f(resid[(size_t)r * Nc + col]);
                    C[(size_t)r * Nc + col] = f2bf(v);
                }
            }
        }
    }
}

// ---------------------------------------------------------------- layer-1 aggregation (from Y [N,256])
__global__ __launch_bounds__(256) void k_agg(const ushort* __restrict__ Y,
                                             const int* __restrict__ row_ptr,
                                             const int* __restrict__ esrt,
                                             const float* __restrict__ bias,
                                             ushort* __restrict__ Xout,
                                             int n) {
    int wid = (blockIdx.x * blockDim.x + threadIdx.x) >> 6;
    int lane = threadIdx.x & 63;
    if (wid >= n) return;
    int beg = row_ptr[wid], end = row_ptr[wid + 1];
    float self = bf2f(Y[(size_t)wid * 256 + lane]);
    float bv = bias[lane];
    float a0 = 0.f, a1 = 0.f, a2 = 0.f;
    int c0 = 0, c1 = 0, c2 = 0;
    int e = beg;
    for (; e + 4 <= end; e += 4) {
        int p0 = esrt[e], p1 = esrt[e + 1], p2 = esrt[e + 2], p3 = esrt[e + 3];
        float v0 = bf2f(Y[(size_t)(p0 & 0x1FFFF) * 256 + 64 + ((p0 >> 17) << 6) + lane]);
        float v1 = bf2f(Y[(size_t)(p1 & 0x1FFFF) * 256 + 64 + ((p1 >> 17) << 6) + lane]);
        float v2 = bf2f(Y[(size_t)(p2 & 0x1FFFF) * 256 + 64 + ((p2 >> 17) << 6) + lane]);
        float v3 = bf2f(Y[(size_t)(p3 & 0x1FFFF) * 256 + 64 + ((p3 >> 17) << 6) + lane]);
        int r0 = p0 >> 17, r1 = p1 >> 17, r2 = p2 >> 17, r3 = p3 >> 17;
        if (r0 == 0) { a0 += v0; c0++; } else if (r0 == 1) { a1 += v0; c1++; } else { a2 += v0; c2++; }
        if (r1 == 0) { a0 += v1; c0++; } else if (r1 == 1) { a1 += v1; c1++; } else { a2 += v1; c2++; }
        if (r2 == 0) { a0 += v2; c0++; } else if (r2 == 1) { a1 += v2; c1++; } else { a2 += v2; c2++; }
        if (r3 == 0) { a0 += v3; c0++; } else if (r3 == 1) { a1 += v3; c1++; } else { a2 += v3; c2++; }
    }
    for (; e < end; ++e) {
        int p = esrt[e];
        int r = p >> 17;
        float v = bf2f(Y[(size_t)(p & 0x1FFFF) * 256 + 64 + (r << 6) + lane]);
        if (r == 0) { a0 += v; c0++; } else if (r == 1) { a1 += v; c1++; } else { a2 += v; c2++; }
    }
    float res = self + bv;
    if (c0) res += a0 / (float)c0;
    if (c1) res += a1 / (float)c1;
    if (c2) res += a2 / (float)c2;
    res = fmaxf(res, 0.f);
    Xout[(size_t)wid * 64 + lane] = f2bf(res);
}

// ---------------------------------------------------------------- agg-first (layers 2/3)
// Gathers raw X rows (12.8 MB table), writes Xagg[N,256] = [x | mean0 | mean1 | mean2]
__global__ __launch_bounds__(256) void k_aggX(const ushort* __restrict__ X,
                                              const int* __restrict__ row_ptr,
                                              const int* __restrict__ esrt,
                                              ushort* __restrict__ Xagg, int n) {
    int wid = (blockIdx.x * blockDim.x + threadIdx.x) >> 6;
    int lane = threadIdx.x & 63;
    if (wid >= n) return;
    int beg = row_ptr[wid], end = row_ptr[wid + 1];
    ushort self = X[(size_t)wid * 64 + lane];
    float a0 = 0.f, a1 = 0.f, a2 = 0.f;
    int c0 = 0, c1 = 0, c2 = 0;
    int e = beg;
    for (; e + 4 <= end; e += 4) {
        int p0 = esrt[e], p1 = esrt[e + 1], p2 = esrt[e + 2], p3 = esrt[e + 3];
        float v0 = bf2f(X[(size_t)(p0 & 0x1FFFF) * 64 + lane]);
        float v1 = bf2f(X[(size_t)(p1 & 0x1FFFF) * 64 + lane]);
        float v2 = bf2f(X[(size_t)(p2 & 0x1FFFF) * 64 + lane]);
        float v3 = bf2f(X[(size_t)(p3 & 0x1FFFF) * 64 + lane]);
        int r0 = p0 >> 17, r1 = p1 >> 17, r2 = p2 >> 17, r3 = p3 >> 17;
        if (r0 == 0) { a0 += v0; c0++; } else if (r0 == 1) { a1 += v0; c1++; } else { a2 += v0; c2++; }
        if (r1 == 0) { a0 += v1; c0++; } else if (r1 == 1) { a1 += v1; c1++; } else { a2 += v1; c2++; }
        if (r2 == 0) { a0 += v2; c0++; } else if (r2 == 1) { a1 += v2; c1++; } else { a2 += v2; c2++; }
        if (r3 == 0) { a0 += v3; c0++; } else if (r3 == 1) { a1 += v3; c1++; } else { a2 += v3; c2++; }
    }
    for (; e < end; ++e) {
        int p = esrt[e];
        int r = p >> 17;
        float v = bf2f(X[(size_t)(p & 0x1FFFF) * 64 + lane]);
        if (r == 0) { a0 += v; c0++; } else if (r == 1) { a1 += v; c1++; } else { a2 += v; c2++; }
    }
    size_t base = (size_t)wid * 256;
    Xagg[base + lane] = self;
    Xagg[base + 64 + lane]  = f2bf(c0 ? a0 / (float)c0 : 0.f);
    Xagg[base + 128 + lane] = f2bf(c1 ? a1 / (float)c1 : 0.f);
    Xagg[base + 192 + lane] = f2bf(c2 ? a2 / (float)c2 : 0.f);
}

// ---------------------------------------------------------------- node head
__global__ __launch_bounds__(256) void k_nodehead(const ushort* __restrict__ X3,
                                                  const float* __restrict__ nw1,
                                                  const float* __restrict__ nb1,
                                                  const float* __restrict__ nw2,
                                                  const float* __restrict__ nb2,
                                                  float* __restrict__ out, int n) {
    __shared__ float w1[64 * 32];
    __shared__ float w2[32 * 2];
    __shared__ float b1s[32];
    __shared__ float b2s[2];
    int tid = threadIdx.x;
    for (int i = tid; i < 64 * 32; i += 256) w1[i] = nw1[i];
    for (int i = tid; i < 32 * 2; i += 256) w2[i] = nw2[i];
    if (tid < 32) b1s[tid] = nb1[tid];
    if (tid < 2) b2s[tid] = nb2[tid];
    __syncthreads();
    int g = blockIdx.x * blockDim.x + tid;
    if (g >= n) return;
    float x[64];
    const uint4* xr = (const uint4*)(X3 + (size_t)g * 64);
    #pragma unroll
    for (int q = 0; q < 8; ++q) {
        uint4 u = xr[q];
        x[q * 8 + 0] = bflo(u.x); x[q * 8 + 1] = bfhi(u.x);
        x[q * 8 + 2] = bflo(u.y); x[q * 8 + 3] = bfhi(u.y);
        x[q * 8 + 4] = bflo(u.z); x[q * 8 + 5] = bfhi(u.z);
        x[q * 8 + 6] = bflo(u.w); x[q * 8 + 7] = bfhi(u.w);
    }
    float o0 = b2s[0], o1 = b2s[1];
    for (int j = 0; j < 32; ++j) {
        float h = b1s[j];
        #pragma unroll
        for (int k = 0; k < 64; ++k) h += x[k] * w1[k * 32 + j];
        h = fmaxf(h, 0.f);
        o0 += h * w2[j * 2 + 0];
        o1 += h * w2[j * 2 + 1];
    }
    out[g * 2 + 0] = o0;
    out[g * 2 + 1] = o1;
}

// ---------------------------------------------------------------- edge head (dst-sorted, split A/B tables)
__global__ __launch_bounds__(256) void k_edgehead(const ushort* __restrict__ Abuf,
                                                  const ushort* __restrict__ Bbuf,
                                                  const int* __restrict__ esrt,
                                                  const int* __restrict__ dstp,
                                                  const int* __restrict__ eid,
                                                  const float* __restrict__ eb1,
                                                  const float* __restrict__ ew2,
                                                  const float* __restrict__ eb2,
                                                  const float* __restrict__ ew3,
                                                  const float* __restrict__ eb3,
                                                  float* __restrict__ out, int E) {
    __shared__ float w2[64 * 32];
    __shared__ float w3[32 * 3];
    __shared__ float b1s[64];
    __shared__ float b2s[32];
    __shared__ float b3s[3];
    int tid = threadIdx.x;
    for (int i = tid; i < 64 * 32; i += 256) w2[i] = ew2[i];
    for (int i = tid; i < 32 * 3; i += 256) w3[i] = ew3[i];
    if (tid < 64) b1s[tid] = eb1[tid];
    if (tid < 32) b2s[tid] = eb2[tid];
    if (tid < 3) b3s[tid] = eb3[tid];
    __syncthreads();
    int p = blockIdx.x * blockDim.x + tid;
    if (p >= E) return;
    int s = esrt[p] & 0x1FFFF;
    int d = dstp[p];
    int e = eid[p];
    const uint4* Ar = (const uint4*)(Abuf + (size_t)s * 64);
    uint4 a4[8];
    #pragma unroll
    for (int q = 0; q < 8; ++q) a4[q] = Ar[q];
    const uint4* Br = (const uint4*)(Bbuf + (size_t)d * 64);
    float h2[32];
    #pragma unroll
    for (int j = 0; j < 32; ++j) h2[j] = 0.f;
    #pragma unroll
    for (int q = 0; q < 8; ++q) {
        uint4 ua = a4[q], ub = Br[q];
        float af[8], bfv[8];
        af[0] = bflo(ua.x); af[1] = bfhi(ua.x); af[2] = bflo(ua.y); af[3] = bfhi(ua.y);
        af[4] = bflo(ua.z); af[5] = bfhi(ua.z); af[6] = bflo(ua.w); af[7] = bfhi(ua.w);
        bfv[0] = bflo(ub.x); bfv[1] = bfhi(ub.x); bfv[2] = bflo(ub.y); bfv[3] = bfhi(ub.y);
        bfv[4] = bflo(ub.z); bfv[5] = bfhi(ub.z); bfv[6] = bflo(ub.w); bfv[7] = bfhi(ub.w);
        #pragma unroll
        for (int t = 0; t < 8; ++t) {
            int k = q * 8 + t;
            float h1 = fmaxf(af[t] + bfv[t] + b1s[k], 0.f);
            #pragma unroll
            for (int j = 0; j < 32; ++j) h2[j] += h1 * w2[k * 32 + j];
        }
    }
    float o0 = b3s[0], o1 = b3s[1], o2 = b3s[2];
    #pragma unroll
    for (int j = 0; j < 32; ++j) {
        float hh = fmaxf(h2[j] + b2s[j], 0.f);
        o0 += hh * w3[j * 3 + 0];
        o1 += hh * w3[j * 3 + 1];
        o2 += hh * w3[j * 3 + 2];
    }
    out[200000 + (size_t)e * 3 + 0] = o0;
    out[200000 + (size_t)e * 3 + 1] = o1;
    out[200000 + (size_t)e * 3 + 2] = o2;
}

// ---------------------------------------------------------------- launch
extern "C" void kernel_launch(void* const* d_in, const int* in_sizes, int n_in,
                              void* d_out, int out_size, void* d_ws, size_t ws_size,
                              hipStream_t stream) {
    const float* x     = (const float*)d_in[0];
    const int*   ei    = (const int*)d_in[1];
    const int*   et    = (const int*)d_in[2];
    const float* W1    = (const float*)d_in[3];
    const float* root1 = (const float*)d_in[4];
    const float* b1    = (const float*)d_in[5];
    const float* W2    = (const float*)d_in[6];
    const float* root2 = (const float*)d_in[7];
    const float* b2    = (const float*)d_in[8];
    const float* W3    = (const float*)d_in[9];
    const float* root3 = (const float*)d_in[10];
    const float* b3    = (const float*)d_in[11];
    const float* nw1   = (const float*)d_in[12];
    const float* nb1   = (const float*)d_in[13];
    const float* nw2   = (const float*)d_in[14];
    const float* nb2   = (const float*)d_in[15];
    const float* ew1   = (const float*)d_in[16];
    const float* eb1   = (const float*)d_in[17];
    const float* ew2   = (const float*)d_in[18];
    const float* eb2   = (const float*)d_in[19];
    const float* ew3   = (const float*)d_in[20];
    const float* eb3   = (const float*)d_in[21];
    float* out = (float*)d_out;

    const int N = MN, E = ME;
    const int* srcv = ei;
    const int* dstv = ei + E;

    char* w = (char*)d_ws;
    ushort* Yb   = (ushort*)w; w += (size_t)N * 256 * 2;  // Y (L1) / Xagg (L2,L3) / Abuf+Bbuf (edge)
    ushort* X1b  = (ushort*)w; w += (size_t)N * 64 * 2;
    ushort* X2b  = (ushort*)w; w += (size_t)N * 64 * 2;
    ushort* X3b  = (ushort*)w; w += (size_t)N * 64 * 2;
    ushort* BT1  = (ushort*)w; w += 256 * 800 * 2;
    ushort* BT2s = (ushort*)w; w += 64 * 256 * 2;
    ushort* BT3s = (ushort*)w; w += 64 * 256 * 2;
    ushort* BTa  = (ushort*)w; w += 64 * 64 * 2;
    ushort* BTb  = (ushort*)w; w += 64 * 64 * 2;
    int* deg     = (int*)w; w += (size_t)N * 4;
    int* row_ptr = (int*)w; w += (size_t)(N + 1) * 4;
    int* cursor  = (int*)w; w += (size_t)N * 4;
    int* esrt    = (int*)w; w += (size_t)E * 4;
    int* dstp    = (int*)w; w += (size_t)E * 4;
    int* eid     = (int*)w; w += (size_t)E * 4;
    int* csums   = (int*)w; w += 512 * 4;

    ushort* Xagg = Yb;
    ushort* Abuf = Yb;
    ushort* Bbuf = Yb + (size_t)N * 64;

    // ---- CSR build
    hipMemsetAsync(deg, 0, N * sizeof(int), stream);
    k_deg<<<(E + 255) / 256, 256, 0, stream>>>(dstv, deg, E);
    int nchunks = (N + 255) / 256;
    k_scan1<<<nchunks, 256, 0, stream>>>(deg, row_ptr, csums, N);
    k_scan2<<<1, 512, 0, stream>>>(csums, nchunks);
    k_scan3<<<(N + 256) / 256, 256, 0, stream>>>(row_ptr, csums, cursor, N, E);
    k_fill<<<(E + 255) / 256, 256, 0, stream>>>(srcv, dstv, et, cursor, esrt, dstp, eid, E);

    // ---- weight packs
    k_pack_bt<<<(256 * 800 + 255) / 256, 256, 0, stream>>>(root1, W1, BT1, KIN, 800);
    k_pack_stack<<<(64 * 256 + 255) / 256, 256, 0, stream>>>(root2, W2, BT2s);
    k_pack_stack<<<(64 * 256 + 255) / 256, 256, 0, stream>>>(root3, W3, BT3s);
    k_packab<<<(64 * 64 + 255) / 256, 256, 0, stream>>>(ew1, BTa, BTb);

    int gx = (N + 127) / 128;  // 782
    int agg_grid = (N * 64 + 255) / 256;

    // ---- layer 1: transform-first (A fp32 fused-convert), then aggregate from Y
    k_mm<true, 256><<<dim3(gx, 1), 512, 0, stream>>>(x, BT1, Yb, N, KIN, 800, 256,
                                                     nullptr, nullptr, 0);
    k_agg<<<agg_grid, 256, 0, stream>>>(Yb, row_ptr, esrt, b1, X1b, N);

    // ---- layer 2: aggregate-first, fused GEMM epilogue (bias+relu)
    k_aggX<<<agg_grid, 256, 0, stream>>>(X1b, row_ptr, esrt, Xagg, N);
    k_mm<false, 64><<<dim3(gx, 1), 512, 0, stream>>>(Xagg, BT2s, X2b, N, 256, 256, 64,
                                                     b2, nullptr, 1);

    // ---- layer 3: aggregate-first, fused epilogue (bias + residual X1, no relu)
    k_aggX<<<agg_grid, 256, 0, stream>>>(X2b, row_ptr, esrt, Xagg, N);
    k_mm<false, 64><<<dim3(gx, 1), 512, 0, stream>>>(Xagg, BT3s, X3b, N, 256, 256, 64,
                                                     b3, X1b, 0);

    // ---- node head
    k_nodehead<<<(N + 255) / 256, 256, 0, stream>>>(X3b, nw1, nb1, nw2, nb2, out, N);

    // ---- edge head: split A/B tables (12.8 MB each), dst-sorted traversal
    k_mm<false, 64><<<dim3(gx, 1), 512, 0, stream>>>(X3b, BTa, Abuf, N, 64, 64, 64,
                                                     nullptr, nullptr, 0);
    k_mm<false, 64><<<dim3(gx, 1), 512, 0, stream>>>(X3b, BTb, Bbuf, N, 64, 64, 64,
                                                     nullptr, nullptr, 0);
    k_edgehead<<<(E + 255) / 256, 256, 0, stream>>>(Abuf, Bbuf, esrt, dstp, eid,
                                                    eb1, ew2, eb2, ew3, eb3, out, E);
}